// Round 2
// baseline (13632.013 us; speedup 1.0000x reference)
//
#include <hip/hip_runtime.h>

// Problem dims (fixed)
#define NB 4096   // B
#define NL 7      // L
#define ND 1024   // D
#define NH 1024   // H
#define NT 6      // T
#define NSTEP 5   // effective scan steps (t = 0..4)
#define GAP 0.02f // gumbel top-2 gap below which we recompute the row in fp32

typedef __attribute__((ext_vector_type(8))) short bf16x8;
typedef __attribute__((ext_vector_type(4))) float f32x4;

// ---------------- threefry2x32 (JAX-compatible, 20 rounds) ----------------
__device__ __forceinline__ unsigned rotl32(unsigned x, int r) {
  return (x << r) | (x >> (32 - r));
}

__device__ __forceinline__ void threefry2x32(unsigned k0, unsigned k1,
                                             unsigned x0, unsigned x1,
                                             unsigned& o0, unsigned& o1) {
  unsigned ks2 = k0 ^ k1 ^ 0x1BD11BDAu;
#define TFR(R) { x0 += x1; x1 = rotl32(x1, (R)); x1 ^= x0; }
  x0 += k0; x1 += k1;
  TFR(13) TFR(15) TFR(26) TFR(6)
  x0 += k1; x1 += ks2 + 1u;
  TFR(17) TFR(29) TFR(16) TFR(24)
  x0 += ks2; x1 += k0 + 2u;
  TFR(13) TFR(15) TFR(26) TFR(6)
  x0 += k0; x1 += k1 + 3u;
  TFR(17) TFR(29) TFR(16) TFR(24)
  x0 += k1; x1 += ks2 + 4u;
  TFR(13) TFR(15) TFR(26) TFR(6)
  x0 += ks2; x1 += k0 + 5u;
#undef TFR
  o0 = x0; o1 = x1;
}

__device__ __forceinline__ float gumbel_for(int b, int j) {
  unsigned o0, o1;
  threefry2x32(0u, 42u, 0u, (unsigned)(b * 28 + j), o0, o1);
  unsigned bits = o0 ^ o1;
  const float TINY = 1.17549435e-38f;
  float u = __uint_as_float((bits >> 9) | 0x3f800000u) - 1.0f;
  u = fmaxf(TINY, u + TINY);
  return -logf(-logf(u));
}

// ---------------- bf16 hi/lo split ----------------
__device__ __forceinline__ unsigned short f2bf(float f) {
  unsigned u = __float_as_uint(f);
  unsigned r = u + 0x7FFFu + ((u >> 16) & 1u);
  return (unsigned short)(r >> 16);
}
__device__ __forceinline__ float bf2f(unsigned short h) {
  return __uint_as_float(((unsigned)h) << 16);
}

__global__ __launch_bounds__(256) void k_split(
    const float* __restrict__ x, unsigned short* __restrict__ hi,
    unsigned short* __restrict__ lo) {
  const size_t i = ((size_t)blockIdx.x * 256 + threadIdx.x) * 4;
  float4 v = *(const float4*)(x + i);
  ushort4 h, l;
  h.x = f2bf(v.x); l.x = f2bf(v.x - bf2f(h.x));
  h.y = f2bf(v.y); l.y = f2bf(v.y - bf2f(h.y));
  h.z = f2bf(v.z); l.z = f2bf(v.z - bf2f(h.z));
  h.w = f2bf(v.w); l.w = f2bf(v.w - bf2f(h.w));
  *(ushort4*)(hi + i) = h;
  *(ushort4*)(lo + i) = l;
}

// ---------------- shared 64x64 fp32 tile core (g1/g2/gemm_bias) ------
__device__ __forceinline__ void tile_compute(const float (*As)[68],
                                             const float (*Bs)[68],
                                             float acc[4][4], int tx, int ty) {
#pragma unroll
  for (int kk = 0; kk < 16; ++kk) {
    float4 a  = *(const float4*)&As[kk][ty * 4];
    float4 bb = *(const float4*)&Bs[kk][tx * 4];
    acc[0][0] += a.x * bb.x; acc[0][1] += a.x * bb.y; acc[0][2] += a.x * bb.z; acc[0][3] += a.x * bb.w;
    acc[1][0] += a.y * bb.x; acc[1][1] += a.y * bb.y; acc[1][2] += a.y * bb.z; acc[1][3] += a.y * bb.w;
    acc[2][0] += a.z * bb.x; acc[2][1] += a.z * bb.y; acc[2][2] += a.z * bb.z; acc[2][3] += a.z * bb.w;
    acc[3][0] += a.w * bb.x; acc[3][1] += a.w * bb.y; acc[3][2] += a.w * bb.z; acc[3][3] += a.w * bb.w;
  }
}

#define TILE_DECLS \
  __shared__ float As[16][68]; \
  __shared__ float Bs[16][68]; \
  float acc[4][4] = {}; \
  const int tid = threadIdx.x; \
  const int tx = tid & 15, ty = tid >> 4; \
  const int row0 = blockIdx.y * 64, col0 = blockIdx.x * 64; \
  const int lm = tid >> 2; \
  const int lk4 = (tid & 3) * 4;

#define STORE_AS(av) { As[lk4+0][lm]=(av).x; As[lk4+1][lm]=(av).y; As[lk4+2][lm]=(av).z; As[lk4+3][lm]=(av).w; }
#define STORE_BS(bv) { Bs[lk4+0][lm]=(bv).x; Bs[lk4+1][lm]=(bv).y; Bs[lk4+2][lm]=(bv).z; Bs[lk4+3][lm]=(bv).w; }

// ---------------- G1: edge_all[t,b,:] for t=0..4 (fp32) ----------------
__global__ __launch_bounds__(256) void g1_edge(
    const float* __restrict__ enc, const int* __restrict__ xes,
    const float* __restrict__ Wh, const float* __restrict__ Wv,
    const float* __restrict__ Wsh, const float* __restrict__ Wsv,
    float* __restrict__ edge_all) {
  TILE_DECLS
  const int r = row0 + lm;
  const int b = r & (NB - 1);
  const int t = r >> 12;
  const int hi = xes[(b * NT + t) * 3 + 0];
  const int vi = xes[(b * NT + t) * 3 + 1];
  const int tt = xes[(b * NT + t) * 3 + 2];

  for (int seg = 0; seg < 4; ++seg) {
    const float* Wp = (seg == 0) ? Wh : (seg == 1) ? Wv : (seg == 2) ? Wsh : Wsv;
    const int li = (seg & 1) ? vi : hi;
    const bool act = ((seg >> 1) == 0) == (tt == 0);
    const float* arow = enc + (((size_t)b * NL + li) << 10);
    const float* brow = Wp + ((size_t)(col0 + lm) << 10);
    for (int k0 = 0; k0 < ND; k0 += 16) {
      float4 av = make_float4(0.f, 0.f, 0.f, 0.f);
      if (act) av = *(const float4*)(arow + k0 + lk4);
      STORE_AS(av)
      float4 bv = *(const float4*)(brow + k0 + lk4);
      STORE_BS(bv)
      __syncthreads();
      tile_compute(As, Bs, acc, tx, ty);
      __syncthreads();
    }
  }
#pragma unroll
  for (int i = 0; i < 4; ++i) {
    float4 v = make_float4(acc[i][0], acc[i][1], acc[i][2], acc[i][3]);
    *(float4*)(edge_all + ((size_t)(row0 + ty * 4 + i) << 10) + col0 + tx * 4) = v;
  }
}

// ---------------- G2: st[b,h] = max(0, max_t (edge_all @ We^T)) ---------------
__global__ __launch_bounds__(256) void g2_stmax(
    const float* __restrict__ edge_all, const float* __restrict__ We,
    unsigned* __restrict__ st) {
  TILE_DECLS
  const float* arow = edge_all + ((size_t)(row0 + lm) << 10);
  const float* brow = We + ((size_t)(col0 + lm) << 10);
  for (int k0 = 0; k0 < NH; k0 += 16) {
    float4 av = *(const float4*)(arow + k0 + lk4);
    STORE_AS(av)
    float4 bv = *(const float4*)(brow + k0 + lk4);
    STORE_BS(bv)
    __syncthreads();
    tile_compute(As, Bs, acc, tx, ty);
    __syncthreads();
  }
#pragma unroll
  for (int i = 0; i < 4; ++i) {
    const int r = row0 + ty * 4 + i;
    const int b = r & (NB - 1);
#pragma unroll
    for (int j = 0; j < 4; ++j) {
      unsigned val = __float_as_uint(fmaxf(acc[i][j], 0.f));
      atomicMax(&st[(size_t)b * NH + col0 + tx * 4 + j], val);
    }
  }
}

// ---------------- C = A @ Bw^T + bias (A optionally gathered) --------
__global__ __launch_bounds__(256) void gemm_bias(
    const float* __restrict__ A, const int* __restrict__ gidx,
    const float* __restrict__ enc, const float* __restrict__ Bw,
    const float* __restrict__ bias, float* __restrict__ C) {
  TILE_DECLS
  const int r = row0 + lm;
  const float* arow = gidx ? (enc + (((size_t)r * NL + gidx[r]) << 10))
                           : (A + ((size_t)r << 10));
  const float* brow = Bw + ((size_t)(col0 + lm) << 10);
  for (int k0 = 0; k0 < ND; k0 += 16) {
    float4 av = *(const float4*)(arow + k0 + lk4);
    STORE_AS(av)
    float4 bv = *(const float4*)(brow + k0 + lk4);
    STORE_BS(bv)
    __syncthreads();
    tile_compute(As, Bs, acc, tx, ty);
    __syncthreads();
  }
#pragma unroll
  for (int i = 0; i < 4; ++i) {
    const int rr = row0 + ty * 4 + i;
    const int n0 = col0 + tx * 4;
    float4 v = make_float4(acc[i][0] + bias[n0 + 0], acc[i][1] + bias[n0 + 1],
                           acc[i][2] + bias[n0 + 2], acc[i][3] + bias[n0 + 3]);
    *(float4*)(C + ((size_t)rr << 10) + n0) = v;
  }
}

// ---------------- G5 (bf16 MFMA): fused ctx GEMM + tanh + V4 reduce --------
__global__ __launch_bounds__(256) void g5_mfma(
    const unsigned short* __restrict__ Ahi, const unsigned short* __restrict__ Alo,
    const unsigned short* __restrict__ Bhi, const unsigned short* __restrict__ Blo,
    const float* __restrict__ inp, const float* __restrict__ bc,
    const float* __restrict__ V4, float* __restrict__ att) {
  __shared__ unsigned short sAhi[4096], sAlo[4096], sBhi[4096], sBlo[4096];
  __shared__ float red[128][32];

  const int tid = threadIdx.x;
  const int row0 = blockIdx.x * 128;   // M-tile (224)
  const int ncol0 = blockIdx.y * 128;  // N-tile (32)

  const int s0 = tid, s1 = tid + 256;
  const int c0 = s0 >> 7, r0 = s0 & 127;
  const int c1 = s1 >> 7, r1 = s1 & 127;
  size_t aoff0 = (size_t)(row0 + r0) * ND + c0 * 8;
  size_t aoff1 = (size_t)(row0 + r1) * ND + c1 * 8;
  size_t boff0 = (size_t)(ncol0 + r0) * ND + c0 * 8;
  size_t boff1 = (size_t)(ncol0 + r1) * ND + c1 * 8;

  const int wave = tid >> 6, lane = tid & 63;
  const int wm = wave >> 1, wn = wave & 1;
  const int q = lane >> 4, m16 = lane & 15;

  f32x4 acc[4][4] = {};

  for (int kt = 0; kt < 32; ++kt) {
    bf16x8 vah0 = *(const bf16x8*)(Ahi + aoff0);
    bf16x8 vah1 = *(const bf16x8*)(Ahi + aoff1);
    bf16x8 val0 = *(const bf16x8*)(Alo + aoff0);
    bf16x8 val1 = *(const bf16x8*)(Alo + aoff1);
    bf16x8 vbh0 = *(const bf16x8*)(Bhi + boff0);
    bf16x8 vbh1 = *(const bf16x8*)(Bhi + boff1);
    bf16x8 vbl0 = *(const bf16x8*)(Blo + boff0);
    bf16x8 vbl1 = *(const bf16x8*)(Blo + boff1);
    *(bf16x8*)&sAhi[s0 * 8] = vah0;
    *(bf16x8*)&sAhi[s1 * 8] = vah1;
    *(bf16x8*)&sAlo[s0 * 8] = val0;
    *(bf16x8*)&sAlo[s1 * 8] = val1;
    *(bf16x8*)&sBhi[s0 * 8] = vbh0;
    *(bf16x8*)&sBhi[s1 * 8] = vbh1;
    *(bf16x8*)&sBlo[s0 * 8] = vbl0;
    *(bf16x8*)&sBlo[s1 * 8] = vbl1;
    __syncthreads();

    bf16x8 bh[4], bl[4];
#pragma unroll
    for (int tn = 0; tn < 4; ++tn) {
      const int nl = wn * 64 + tn * 16 + m16;
      bh[tn] = *(const bf16x8*)&sBhi[(q * 128 + nl) * 8];
      bl[tn] = *(const bf16x8*)&sBlo[(q * 128 + nl) * 8];
    }
#pragma unroll
    for (int tm = 0; tm < 4; ++tm) {
      const int ml = wm * 64 + tm * 16 + m16;
      bf16x8 ah = *(const bf16x8*)&sAhi[(q * 128 + ml) * 8];
      bf16x8 al = *(const bf16x8*)&sAlo[(q * 128 + ml) * 8];
#pragma unroll
      for (int tn = 0; tn < 4; ++tn) {
        acc[tm][tn] = __builtin_amdgcn_mfma_f32_16x16x32_bf16(ah, bh[tn], acc[tm][tn], 0, 0, 0);
        acc[tm][tn] = __builtin_amdgcn_mfma_f32_16x16x32_bf16(al, bh[tn], acc[tm][tn], 0, 0, 0);
        acc[tm][tn] = __builtin_amdgcn_mfma_f32_16x16x32_bf16(ah, bl[tn], acc[tm][tn], 0, 0, 0);
      }
    }
    __syncthreads();
    aoff0 += 32; aoff1 += 32; boff0 += 32; boff1 += 32;
  }

  const int kq = ncol0 >> 10;
  float rowsum[16];
#pragma unroll
  for (int i = 0; i < 16; ++i) rowsum[i] = 0.f;
#pragma unroll
  for (int tm = 0; tm < 4; ++tm) {
#pragma unroll
    for (int tn = 0; tn < 4; ++tn) {
      const int n = ncol0 + wn * 64 + tn * 16 + m16;
      const int h = n & (NH - 1);
      const float v4 = V4[kq * NH + h];
      const float bcv = bc[kq * NH + h];
#pragma unroll
      for (int j = 0; j < 4; ++j) {
        const int R = row0 + wm * 64 + tm * 16 + q * 4 + j;
        const int b = R / NL;
        float val = acc[tm][tn][j] + inp[(size_t)b * NH + h] + bcv;
        rowsum[tm * 4 + j] += v4 * tanhf(val);
      }
    }
  }
#pragma unroll
  for (int tm = 0; tm < 4; ++tm)
#pragma unroll
    for (int j = 0; j < 4; ++j)
      red[wm * 64 + tm * 16 + q * 4 + j][wn * 16 + m16] = rowsum[tm * 4 + j];
  __syncthreads();
  if (tid < 128) {
    float ssum = 0.f;
#pragma unroll
    for (int x = 0; x < 32; ++x) ssum += red[tid][x];
    const int R = row0 + tid;
    const int b = R / NL, l = R - b * NL;
    atomicAdd(&att[b * 28 + kq * NL + l], ssum);
  }
}

// ---------------- elementwise: query chain ----------------
__global__ __launch_bounds__(256) void k_query(
    const float* __restrict__ edge_all, const float* __restrict__ st,
    const float* __restrict__ lin, float* __restrict__ query) {
  const size_t i = (size_t)blockIdx.x * 256 + threadIdx.x;
  float e4 = edge_all[(size_t)4 * NB * NH + i];
  float qt = fmaxf(e4 + st[i], 0.f);
  float l = lin[i];
  float q = fmaxf(qt + l, 0.f);
  q = fmaxf(q + l, 0.f);
  query[i] = q;
}

// ---------------- att finish: mask -> -inf -> 10*tanh ----------------
__global__ __launch_bounds__(256) void k_finish(
    float* __restrict__ att, const int* __restrict__ mask) {
  const int i = blockIdx.x * 256 + threadIdx.x;
  const int b = i / 28;
  const int j = i - b * 28;
  const int l = j % NL;
  float v = att[i];
  att[i] = (mask[b * NL + l] != 0) ? (10.f * tanhf(v)) : -10.f;
}

// ---------------- per-column (over B) softmax stats ----------------
__global__ __launch_bounds__(256) void k_colstats(
    const float* __restrict__ att, float* __restrict__ Mv, float* __restrict__ Sv) {
  const int j = blockIdx.x;
  const int tid = threadIdx.x;
  __shared__ float sm[256];
  float m = -INFINITY;
  for (int b = tid; b < NB; b += 256) m = fmaxf(m, att[b * 28 + j]);
  sm[tid] = m;
  __syncthreads();
  for (int s = 128; s > 0; s >>= 1) {
    if (tid < s) sm[tid] = fmaxf(sm[tid], sm[tid + s]);
    __syncthreads();
  }
  const float M = sm[0];
  __syncthreads();
  float sum = 0.f;
  for (int b = tid; b < NB; b += 256) sum += expf(att[b * 28 + j] - M);
  sm[tid] = sum;
  __syncthreads();
  for (int s = 128; s > 0; s >>= 1) {
    if (tid < s) sm[tid] += sm[tid + s];
    __syncthreads();
  }
  if (tid == 0) { Mv[j] = M; Sv[j] = sm[0]; }
}

// ---------------- sampling + close-call flagging ----------------
__global__ __launch_bounds__(256) void k_sample(
    const float* __restrict__ att, const float* __restrict__ Mv,
    const float* __restrict__ Sv, const int* __restrict__ mask,
    float* __restrict__ out, int* __restrict__ flag) {
  const int b = blockIdx.x * 256 + threadIdx.x;
  if (b >= NB) return;
  float best = -INFINITY, second = -INFINITY;
  int bj = 0;
  for (int j = 0; j < 28; ++j) {
    float y = (att[b * 28 + j] - Mv[j]) - logf(Sv[j]) + gumbel_for(b, j);
    if (y > best) { second = best; best = y; bj = j; }
    else if (y > second) second = y;
  }
  out[b] = (float)bj;
  out[NB + b] = expf(att[b * 28 + bj] - Mv[bj]) / Sv[bj];
  const int* mrow = mask + b * NL;
#pragma unroll
  for (int l = 0; l < NL; ++l)
    out[2 * NB + (size_t)b * NL + l] = (float)(mrow[l] - ((l == bj) ? 1 : 0));
  flag[b] = (best - second < GAP) ? 1 : 0;
}

// ---------------- fp32 fixup for flagged (close-call) rows ----------------
__global__ __launch_bounds__(256) void k_fixup(
    const int* __restrict__ flag, const float* __restrict__ enc,
    const float* __restrict__ Wc, const float* __restrict__ bc,
    const float* __restrict__ V4, const float* __restrict__ inp,
    const float* __restrict__ Mv, const float* __restrict__ Sv,
    const int* __restrict__ mask, float* __restrict__ out) {
  const int b = blockIdx.x;
  if (!flag[b]) return;
  const int tid = threadIdx.x;
  __shared__ float sm[256];
  __shared__ float atts[28];
  for (int j = 0; j < 28; ++j) {
    const int kq = j / NL, l = j % NL;
    const float* er = enc + (((size_t)b * NL + l) << 10);
    float part = 0.f;
    for (int h = tid; h < NH; h += 256) {
      const float* wr = Wc + (((size_t)kq * NH + h) << 10);
      float d = 0.f;
      for (int k = 0; k < ND; k += 4) {
        float4 e = *(const float4*)(er + k);
        float4 w = *(const float4*)(wr + k);
        d += e.x * w.x + e.y * w.y + e.z * w.z + e.w * w.w;
      }
      part += V4[kq * NH + h] * tanhf(d + inp[(size_t)b * NH + h] + bc[kq * NH + h]);
    }
    sm[tid] = part;
    __syncthreads();
    for (int s = 128; s > 0; s >>= 1) {
      if (tid < s) sm[tid] += sm[tid + s];
      __syncthreads();
    }
    if (tid == 0) atts[j] = sm[0];
    __syncthreads();
  }
  if (tid == 0) {
    float best = -INFINITY;
    int bj = 0;
    float bp = 0.f;
    for (int j = 0; j < 28; ++j) {
      const int l = j % NL;
      float a = (mask[b * NL + l] != 0) ? (10.f * tanhf(atts[j])) : -10.f;
      float y = (a - Mv[j]) - logf(Sv[j]) + gumbel_for(b, j);
      if (y > best) { best = y; bj = j; bp = expf(a - Mv[j]) / Sv[j]; }
    }
    out[b] = (float)bj;
    out[NB + b] = bp;
    for (int l = 0; l < NL; ++l)
      out[2 * NB + (size_t)b * NL + l] = (float)(mask[b * NL + l] - ((l == bj) ? 1 : 0));
  }
}

extern "C" void kernel_launch(void* const* d_in, const int* in_sizes, int n_in,
                              void* d_out, int out_size, void* d_ws, size_t ws_size,
                              hipStream_t stream) {
  const float* enc  = (const float*)d_in[0];
  const int*   xes  = (const int*)d_in[1];
  const int*   idx  = (const int*)d_in[2];
  const int*   mask = (const int*)d_in[3];
  const float* Wq   = (const float*)d_in[4];
  const float* bq   = (const float*)d_in[5];
  const float* Wc   = (const float*)d_in[6];
  const float* bc   = (const float*)d_in[7];
  const float* V4   = (const float*)d_in[8];
  const float* Wi   = (const float*)d_in[9];
  const float* bi   = (const float*)d_in[10];
  const float* Wh   = (const float*)d_in[11];
  const float* Wv   = (const float*)d_in[12];
  const float* Wsh  = (const float*)d_in[13];
  const float* Wsv  = (const float*)d_in[14];
  const float* We   = (const float*)d_in[15];
  (void)in_sizes; (void)n_in; (void)out_size; (void)ws_size;

  float* edge_all = (float*)d_ws;                          // [5*NB, NH]
  float* st       = edge_all + (size_t)NSTEP * NB * NH;    // [NB, NH]
  float* lin      = st + (size_t)NB * NH;                  // [NB, NH]
  float* query    = lin + (size_t)NB * NH;                 // [NB, NH]
  float* inp      = query + (size_t)NB * NH;               // [NB, NH]
  float* att      = inp + (size_t)NB * NH;                 // [NB, 28]
  float* Mv       = att + (size_t)NB * 28;                 // [28]
  float* Sv       = Mv + 28;                               // [28]
  int*   flag     = (int*)(Sv + 28);                       // [NB]
  unsigned short* enc_hi = (unsigned short*)(flag + NB);   // [NB*NL, ND]
  unsigned short* enc_lo = enc_hi + (size_t)NB * NL * ND;
  unsigned short* wc_hi  = enc_lo + (size_t)NB * NL * ND;  // [4*NH, ND]
  unsigned short* wc_lo  = wc_hi + (size_t)4 * NH * ND;
  float* out      = (float*)d_out;

  hipMemsetAsync(st, 0, (size_t)NB * NH * sizeof(float), stream);
  hipMemsetAsync(att, 0, (size_t)NB * 28 * sizeof(float), stream);

  dim3 blk(256);
  k_split<<<dim3((NB * NL * ND) / 1024), blk, 0, stream>>>(enc, enc_hi, enc_lo);
  k_split<<<dim3((4 * NH * ND) / 1024), blk, 0, stream>>>(Wc, wc_hi, wc_lo);
  g1_edge<<<dim3(16, 320), blk, 0, stream>>>(enc, xes, Wh, Wv, Wsh, Wsv, edge_all);
  gemm_bias<<<dim3(16, 64), blk, 0, stream>>>(nullptr, idx, enc, Wi, bi, lin);
  g2_stmax<<<dim3(16, 320), blk, 0, stream>>>(edge_all, We, (unsigned*)st);
  k_query<<<dim3((NB * NH) / 256), blk, 0, stream>>>(edge_all, st, lin, query);
  gemm_bias<<<dim3(16, 64), blk, 0, stream>>>(query, nullptr, enc, Wq, bq, inp);
  g5_mfma<<<dim3(224, 32), blk, 0, stream>>>(enc_hi, enc_lo, wc_hi, wc_lo,
                                             inp, bc, V4, att);
  k_finish<<<dim3((NB * 28) / 256), blk, 0, stream>>>(att, mask);
  k_colstats<<<dim3(28), blk, 0, stream>>>(att, Mv, Sv);
  k_sample<<<dim3(NB / 256), blk, 0, stream>>>(att, Mv, Sv, mask, out, flag);
  k_fixup<<<dim3(NB), blk, 0, stream>>>(flag, enc, Wc, bc, V4, inp, Mv, Sv, mask, out);
}

// Round 3
// 5307.601 us; speedup vs baseline: 2.5684x; 2.5684x over previous
//
#include <hip/hip_runtime.h>

// Problem dims (fixed)
#define NB 4096   // B
#define NL 7      // L
#define ND 1024   // D
#define NH 1024   // H
#define NT 6      // T
#define NSTEP 5   // effective scan steps (t = 0..4)
#define GAP 0.02f // gumbel top-2 gap below which we recompute the row in fp32

typedef __attribute__((ext_vector_type(8))) short bf16x8;
typedef __attribute__((ext_vector_type(4))) float f32x4;

// ---------------- threefry2x32 (JAX-compatible, 20 rounds) ----------------
__device__ __forceinline__ unsigned rotl32(unsigned x, int r) {
  return (x << r) | (x >> (32 - r));
}

__device__ __forceinline__ void threefry2x32(unsigned k0, unsigned k1,
                                             unsigned x0, unsigned x1,
                                             unsigned& o0, unsigned& o1) {
  unsigned ks2 = k0 ^ k1 ^ 0x1BD11BDAu;
#define TFR(R) { x0 += x1; x1 = rotl32(x1, (R)); x1 ^= x0; }
  x0 += k0; x1 += k1;
  TFR(13) TFR(15) TFR(26) TFR(6)
  x0 += k1; x1 += ks2 + 1u;
  TFR(17) TFR(29) TFR(16) TFR(24)
  x0 += ks2; x1 += k0 + 2u;
  TFR(13) TFR(15) TFR(26) TFR(6)
  x0 += k0; x1 += k1 + 3u;
  TFR(17) TFR(29) TFR(16) TFR(24)
  x0 += k1; x1 += ks2 + 4u;
  TFR(13) TFR(15) TFR(26) TFR(6)
  x0 += ks2; x1 += k0 + 5u;
#undef TFR
  o0 = x0; o1 = x1;
}

__device__ __forceinline__ float gumbel_for(int b, int j) {
  unsigned o0, o1;
  threefry2x32(0u, 42u, 0u, (unsigned)(b * 28 + j), o0, o1);
  unsigned bits = o0 ^ o1;
  const float TINY = 1.17549435e-38f;
  float u = __uint_as_float((bits >> 9) | 0x3f800000u) - 1.0f;
  u = fmaxf(TINY, u + TINY);
  return -logf(-logf(u));
}

// ---------------- bf16 hi/lo split ----------------
__device__ __forceinline__ unsigned short f2bf(float f) {
  unsigned u = __float_as_uint(f);
  unsigned r = u + 0x7FFFu + ((u >> 16) & 1u);
  return (unsigned short)(r >> 16);
}
__device__ __forceinline__ float bf2f(unsigned short h) {
  return __uint_as_float(((unsigned)h) << 16);
}

__global__ __launch_bounds__(256) void k_split(
    const float* __restrict__ x, unsigned short* __restrict__ hi,
    unsigned short* __restrict__ lo) {
  const size_t i = ((size_t)blockIdx.x * 256 + threadIdx.x) * 4;
  float4 v = *(const float4*)(x + i);
  ushort4 h, l;
  h.x = f2bf(v.x); l.x = f2bf(v.x - bf2f(h.x));
  h.y = f2bf(v.y); l.y = f2bf(v.y - bf2f(h.y));
  h.z = f2bf(v.z); l.z = f2bf(v.z - bf2f(h.z));
  h.w = f2bf(v.w); l.w = f2bf(v.w - bf2f(h.w));
  *(ushort4*)(hi + i) = h;
  *(ushort4*)(lo + i) = l;
}

// ---------------- shared 64x64 fp32 tile core (g1/g2/gemm_bias) ------
__device__ __forceinline__ void tile_compute(const float (*As)[68],
                                             const float (*Bs)[68],
                                             float acc[4][4], int tx, int ty) {
#pragma unroll
  for (int kk = 0; kk < 16; ++kk) {
    float4 a  = *(const float4*)&As[kk][ty * 4];
    float4 bb = *(const float4*)&Bs[kk][tx * 4];
    acc[0][0] += a.x * bb.x; acc[0][1] += a.x * bb.y; acc[0][2] += a.x * bb.z; acc[0][3] += a.x * bb.w;
    acc[1][0] += a.y * bb.x; acc[1][1] += a.y * bb.y; acc[1][2] += a.y * bb.z; acc[1][3] += a.y * bb.w;
    acc[2][0] += a.z * bb.x; acc[2][1] += a.z * bb.y; acc[2][2] += a.z * bb.z; acc[2][3] += a.z * bb.w;
    acc[3][0] += a.w * bb.x; acc[3][1] += a.w * bb.y; acc[3][2] += a.w * bb.z; acc[3][3] += a.w * bb.w;
  }
}

#define TILE_DECLS \
  __shared__ float As[16][68]; \
  __shared__ float Bs[16][68]; \
  float acc[4][4] = {}; \
  const int tid = threadIdx.x; \
  const int tx = tid & 15, ty = tid >> 4; \
  const int row0 = blockIdx.y * 64, col0 = blockIdx.x * 64; \
  const int lm = tid >> 2; \
  const int lk4 = (tid & 3) * 4;

#define STORE_AS(av) { As[lk4+0][lm]=(av).x; As[lk4+1][lm]=(av).y; As[lk4+2][lm]=(av).z; As[lk4+3][lm]=(av).w; }
#define STORE_BS(bv) { Bs[lk4+0][lm]=(bv).x; Bs[lk4+1][lm]=(bv).y; Bs[lk4+2][lm]=(bv).z; Bs[lk4+3][lm]=(bv).w; }

// ---------------- G1: edge_all[t,b,:] for t=0..4 (fp32) ----------------
__global__ __launch_bounds__(256) void g1_edge(
    const float* __restrict__ enc, const int* __restrict__ xes,
    const float* __restrict__ Wh, const float* __restrict__ Wv,
    const float* __restrict__ Wsh, const float* __restrict__ Wsv,
    float* __restrict__ edge_all) {
  TILE_DECLS
  const int r = row0 + lm;
  const int b = r & (NB - 1);
  const int t = r >> 12;
  const int hi = xes[(b * NT + t) * 3 + 0];
  const int vi = xes[(b * NT + t) * 3 + 1];
  const int tt = xes[(b * NT + t) * 3 + 2];

  for (int seg = 0; seg < 4; ++seg) {
    const float* Wp = (seg == 0) ? Wh : (seg == 1) ? Wv : (seg == 2) ? Wsh : Wsv;
    const int li = (seg & 1) ? vi : hi;
    const bool act = ((seg >> 1) == 0) == (tt == 0);
    const float* arow = enc + (((size_t)b * NL + li) << 10);
    const float* brow = Wp + ((size_t)(col0 + lm) << 10);
    for (int k0 = 0; k0 < ND; k0 += 16) {
      float4 av = make_float4(0.f, 0.f, 0.f, 0.f);
      if (act) av = *(const float4*)(arow + k0 + lk4);
      STORE_AS(av)
      float4 bv = *(const float4*)(brow + k0 + lk4);
      STORE_BS(bv)
      __syncthreads();
      tile_compute(As, Bs, acc, tx, ty);
      __syncthreads();
    }
  }
#pragma unroll
  for (int i = 0; i < 4; ++i) {
    float4 v = make_float4(acc[i][0], acc[i][1], acc[i][2], acc[i][3]);
    *(float4*)(edge_all + ((size_t)(row0 + ty * 4 + i) << 10) + col0 + tx * 4) = v;
  }
}

// ---------------- G2: st[b,h] = max(0, max_t (edge_all @ We^T)) ---------------
__global__ __launch_bounds__(256) void g2_stmax(
    const float* __restrict__ edge_all, const float* __restrict__ We,
    unsigned* __restrict__ st) {
  TILE_DECLS
  const float* arow = edge_all + ((size_t)(row0 + lm) << 10);
  const float* brow = We + ((size_t)(col0 + lm) << 10);
  for (int k0 = 0; k0 < NH; k0 += 16) {
    float4 av = *(const float4*)(arow + k0 + lk4);
    STORE_AS(av)
    float4 bv = *(const float4*)(brow + k0 + lk4);
    STORE_BS(bv)
    __syncthreads();
    tile_compute(As, Bs, acc, tx, ty);
    __syncthreads();
  }
#pragma unroll
  for (int i = 0; i < 4; ++i) {
    const int r = row0 + ty * 4 + i;
    const int b = r & (NB - 1);
#pragma unroll
    for (int j = 0; j < 4; ++j) {
      unsigned val = __float_as_uint(fmaxf(acc[i][j], 0.f));
      atomicMax(&st[(size_t)b * NH + col0 + tx * 4 + j], val);
    }
  }
}

// ---------------- C = A @ Bw^T + bias (A optionally gathered) --------
__global__ __launch_bounds__(256) void gemm_bias(
    const float* __restrict__ A, const int* __restrict__ gidx,
    const float* __restrict__ enc, const float* __restrict__ Bw,
    const float* __restrict__ bias, float* __restrict__ C) {
  TILE_DECLS
  const int r = row0 + lm;
  const float* arow = gidx ? (enc + (((size_t)r * NL + gidx[r]) << 10))
                           : (A + ((size_t)r << 10));
  const float* brow = Bw + ((size_t)(col0 + lm) << 10);
  for (int k0 = 0; k0 < ND; k0 += 16) {
    float4 av = *(const float4*)(arow + k0 + lk4);
    STORE_AS(av)
    float4 bv = *(const float4*)(brow + k0 + lk4);
    STORE_BS(bv)
    __syncthreads();
    tile_compute(As, Bs, acc, tx, ty);
    __syncthreads();
  }
#pragma unroll
  for (int i = 0; i < 4; ++i) {
    const int rr = row0 + ty * 4 + i;
    const int n0 = col0 + tx * 4;
    float4 v = make_float4(acc[i][0] + bias[n0 + 0], acc[i][1] + bias[n0 + 1],
                           acc[i][2] + bias[n0 + 2], acc[i][3] + bias[n0 + 3]);
    *(float4*)(C + ((size_t)rr << 10) + n0) = v;
  }
}

// ---------------- G5 (bf16 MFMA): fused ctx GEMM + tanh + V4 reduce --------
__global__ __launch_bounds__(256) void g5_mfma(
    const unsigned short* __restrict__ Ahi, const unsigned short* __restrict__ Alo,
    const unsigned short* __restrict__ Bhi, const unsigned short* __restrict__ Blo,
    const float* __restrict__ inp, const float* __restrict__ bc,
    const float* __restrict__ V4, float* __restrict__ att) {
  __shared__ unsigned short sAhi[4096], sAlo[4096], sBhi[4096], sBlo[4096];
  __shared__ float red[128][32];

  const int tid = threadIdx.x;
  const int row0 = blockIdx.x * 128;   // M-tile (224)
  const int ncol0 = blockIdx.y * 128;  // N-tile (32)

  const int s0 = tid, s1 = tid + 256;
  const int c0 = s0 >> 7, r0 = s0 & 127;
  const int c1 = s1 >> 7, r1 = s1 & 127;
  size_t aoff0 = (size_t)(row0 + r0) * ND + c0 * 8;
  size_t aoff1 = (size_t)(row0 + r1) * ND + c1 * 8;
  size_t boff0 = (size_t)(ncol0 + r0) * ND + c0 * 8;
  size_t boff1 = (size_t)(ncol0 + r1) * ND + c1 * 8;

  const int wave = tid >> 6, lane = tid & 63;
  const int wm = wave >> 1, wn = wave & 1;
  const int q = lane >> 4, m16 = lane & 15;

  f32x4 acc[4][4] = {};

  for (int kt = 0; kt < 32; ++kt) {
    bf16x8 vah0 = *(const bf16x8*)(Ahi + aoff0);
    bf16x8 vah1 = *(const bf16x8*)(Ahi + aoff1);
    bf16x8 val0 = *(const bf16x8*)(Alo + aoff0);
    bf16x8 val1 = *(const bf16x8*)(Alo + aoff1);
    bf16x8 vbh0 = *(const bf16x8*)(Bhi + boff0);
    bf16x8 vbh1 = *(const bf16x8*)(Bhi + boff1);
    bf16x8 vbl0 = *(const bf16x8*)(Blo + boff0);
    bf16x8 vbl1 = *(const bf16x8*)(Blo + boff1);
    *(bf16x8*)&sAhi[s0 * 8] = vah0;
    *(bf16x8*)&sAhi[s1 * 8] = vah1;
    *(bf16x8*)&sAlo[s0 * 8] = val0;
    *(bf16x8*)&sAlo[s1 * 8] = val1;
    *(bf16x8*)&sBhi[s0 * 8] = vbh0;
    *(bf16x8*)&sBhi[s1 * 8] = vbh1;
    *(bf16x8*)&sBlo[s0 * 8] = vbl0;
    *(bf16x8*)&sBlo[s1 * 8] = vbl1;
    __syncthreads();

    bf16x8 bh[4], bl[4];
#pragma unroll
    for (int tn = 0; tn < 4; ++tn) {
      const int nl = wn * 64 + tn * 16 + m16;
      bh[tn] = *(const bf16x8*)&sBhi[(q * 128 + nl) * 8];
      bl[tn] = *(const bf16x8*)&sBlo[(q * 128 + nl) * 8];
    }
#pragma unroll
    for (int tm = 0; tm < 4; ++tm) {
      const int ml = wm * 64 + tm * 16 + m16;
      bf16x8 ah = *(const bf16x8*)&sAhi[(q * 128 + ml) * 8];
      bf16x8 al = *(const bf16x8*)&sAlo[(q * 128 + ml) * 8];
#pragma unroll
      for (int tn = 0; tn < 4; ++tn) {
        acc[tm][tn] = __builtin_amdgcn_mfma_f32_16x16x32_bf16(ah, bh[tn], acc[tm][tn], 0, 0, 0);
        acc[tm][tn] = __builtin_amdgcn_mfma_f32_16x16x32_bf16(al, bh[tn], acc[tm][tn], 0, 0, 0);
        acc[tm][tn] = __builtin_amdgcn_mfma_f32_16x16x32_bf16(ah, bl[tn], acc[tm][tn], 0, 0, 0);
      }
    }
    __syncthreads();
    aoff0 += 32; aoff1 += 32; boff0 += 32; boff1 += 32;
  }

  const int kq = ncol0 >> 10;
  float rowsum[16];
#pragma unroll
  for (int i = 0; i < 16; ++i) rowsum[i] = 0.f;
#pragma unroll
  for (int tm = 0; tm < 4; ++tm) {
#pragma unroll
    for (int tn = 0; tn < 4; ++tn) {
      const int n = ncol0 + wn * 64 + tn * 16 + m16;
      const int h = n & (NH - 1);
      const float v4 = V4[kq * NH + h];
      const float bcv = bc[kq * NH + h];
#pragma unroll
      for (int j = 0; j < 4; ++j) {
        const int R = row0 + wm * 64 + tm * 16 + q * 4 + j;
        const int b = R / NL;
        float val = acc[tm][tn][j] + inp[(size_t)b * NH + h] + bcv;
        rowsum[tm * 4 + j] += v4 * tanhf(val);
      }
    }
  }
#pragma unroll
  for (int tm = 0; tm < 4; ++tm)
#pragma unroll
    for (int j = 0; j < 4; ++j)
      red[wm * 64 + tm * 16 + q * 4 + j][wn * 16 + m16] = rowsum[tm * 4 + j];
  __syncthreads();
  if (tid < 128) {
    float ssum = 0.f;
#pragma unroll
    for (int x = 0; x < 32; ++x) ssum += red[tid][x];
    const int R = row0 + tid;
    const int b = R / NL, l = R - b * NL;
    atomicAdd(&att[b * 28 + kq * NL + l], ssum);
  }
}

// ---------------- elementwise: query chain ----------------
__global__ __launch_bounds__(256) void k_query(
    const float* __restrict__ edge_all, const float* __restrict__ st,
    const float* __restrict__ lin, float* __restrict__ query) {
  const size_t i = (size_t)blockIdx.x * 256 + threadIdx.x;
  float e4 = edge_all[(size_t)4 * NB * NH + i];
  float qt = fmaxf(e4 + st[i], 0.f);
  float l = lin[i];
  float q = fmaxf(qt + l, 0.f);
  q = fmaxf(q + l, 0.f);
  query[i] = q;
}

// ---------------- att finish: mask -> -inf -> 10*tanh ----------------
__global__ __launch_bounds__(256) void k_finish(
    float* __restrict__ att, const int* __restrict__ mask) {
  const int i = blockIdx.x * 256 + threadIdx.x;
  const int b = i / 28;
  const int j = i - b * 28;
  const int l = j % NL;
  float v = att[i];
  att[i] = (mask[b * NL + l] != 0) ? (10.f * tanhf(v)) : -10.f;
}

// ---------------- per-column (over B) softmax stats ----------------
__global__ __launch_bounds__(256) void k_colstats(
    const float* __restrict__ att, float* __restrict__ Mv, float* __restrict__ Sv) {
  const int j = blockIdx.x;
  const int tid = threadIdx.x;
  __shared__ float sm[256];
  float m = -INFINITY;
  for (int b = tid; b < NB; b += 256) m = fmaxf(m, att[b * 28 + j]);
  sm[tid] = m;
  __syncthreads();
  for (int s = 128; s > 0; s >>= 1) {
    if (tid < s) sm[tid] = fmaxf(sm[tid], sm[tid + s]);
    __syncthreads();
  }
  const float M = sm[0];
  __syncthreads();
  float sum = 0.f;
  for (int b = tid; b < NB; b += 256) sum += expf(att[b * 28 + j] - M);
  sm[tid] = sum;
  __syncthreads();
  for (int s = 128; s > 0; s >>= 1) {
    if (tid < s) sm[tid] += sm[tid + s];
    __syncthreads();
  }
  if (tid == 0) { Mv[j] = M; Sv[j] = sm[0]; }
}

// ---------------- sampling + close-call compaction ----------------
__global__ __launch_bounds__(256) void k_sample(
    const float* __restrict__ att, const float* __restrict__ Mv,
    const float* __restrict__ Sv, const int* __restrict__ mask,
    float* __restrict__ out, int* __restrict__ flag,
    int* __restrict__ cnt, int* __restrict__ list) {
  const int b = blockIdx.x * 256 + threadIdx.x;
  if (b >= NB) return;
  float best = -INFINITY, second = -INFINITY;
  int bj = 0;
  for (int j = 0; j < 28; ++j) {
    float y = (att[b * 28 + j] - Mv[j]) - logf(Sv[j]) + gumbel_for(b, j);
    if (y > best) { second = best; best = y; bj = j; }
    else if (y > second) second = y;
  }
  out[b] = (float)bj;
  out[NB + b] = expf(att[b * 28 + bj] - Mv[bj]) / Sv[bj];
  const int* mrow = mask + b * NL;
#pragma unroll
  for (int l = 0; l < NL; ++l)
    out[2 * NB + (size_t)b * NL + l] = (float)(mrow[l] - ((l == bj) ? 1 : 0));
  const int f = (best - second < GAP) ? 1 : 0;
  flag[b] = f;
  if (f) {
    int pos = atomicAdd(cnt, 1);
    list[pos] = b;
  }
}

// ---------------- fp32 att recompute for flagged rows ----------------
// grid (4, 64): blockIdx.x = kq, blockIdx.y = slot over compacted list.
// Each block computes the 7 att entries (b, kq*7+l) in full fp32 and
// overwrites att in place (including mask + 10*tanh finish).
__global__ __launch_bounds__(256) void k_fixup_att(
    const int* __restrict__ cnt, const int* __restrict__ list,
    const float* __restrict__ enc, const float* __restrict__ Wc,
    const float* __restrict__ bc, const float* __restrict__ V4,
    const float* __restrict__ inp, const int* __restrict__ mask,
    float* __restrict__ att) {
  const int kq = blockIdx.x;
  const int tid = threadIdx.x;
  __shared__ float sEnc[NL][ND];
  __shared__ float sm[256];
  const int n = cnt[0];
  for (int it = blockIdx.y; it < n; it += gridDim.y) {
    const int b = list[it];
    // stage the 7 enc rows for this b into LDS
    for (int i = tid; i < NL * 256; i += 256) {
      const int l = i >> 8, c = (i & 255) * 4;
      *(float4*)&sEnc[l][c] = *(const float4*)(enc + (((size_t)b * NL + l) << 10) + c);
    }
    __syncthreads();
    float accl[NL];
#pragma unroll
    for (int l = 0; l < NL; ++l) accl[l] = 0.f;
    for (int hp = 0; hp < 2; ++hp) {
      const int h0 = tid + hp * 512;
      const int h1 = h0 + 256;
      const float* w0 = Wc + (((size_t)kq * NH + h0) << 10);
      const float* w1 = Wc + (((size_t)kq * NH + h1) << 10);
      float d0[NL], d1[NL];
#pragma unroll
      for (int l = 0; l < NL; ++l) { d0[l] = 0.f; d1[l] = 0.f; }
      for (int k = 0; k < ND; k += 4) {
        float4 a = *(const float4*)(w0 + k);
        float4 c = *(const float4*)(w1 + k);
#pragma unroll
        for (int l = 0; l < NL; ++l) {
          float4 e = *(const float4*)&sEnc[l][k];
          d0[l] += a.x * e.x + a.y * e.y + a.z * e.z + a.w * e.w;
          d1[l] += c.x * e.x + c.y * e.y + c.z * e.z + c.w * e.w;
        }
      }
      const float i0 = inp[(size_t)b * NH + h0], i1 = inp[(size_t)b * NH + h1];
      const float b0 = bc[kq * NH + h0], b1 = bc[kq * NH + h1];
      const float v0 = V4[kq * NH + h0], v1 = V4[kq * NH + h1];
#pragma unroll
      for (int l = 0; l < NL; ++l)
        accl[l] += v0 * tanhf(d0[l] + i0 + b0) + v1 * tanhf(d1[l] + i1 + b1);
    }
    // reduce each l over the block, write fixed att
    for (int l = 0; l < NL; ++l) {
      sm[tid] = accl[l];
      __syncthreads();
      for (int s = 128; s > 0; s >>= 1) {
        if (tid < s) sm[tid] += sm[tid + s];
        __syncthreads();
      }
      if (tid == 0) {
        float a = (mask[b * NL + l] != 0) ? (10.f * tanhf(sm[0])) : -10.f;
        att[b * 28 + kq * NL + l] = a;
      }
      __syncthreads();
    }
    __syncthreads();
  }
}

// ---------------- re-sample flagged rows with fixed att ----------------
__global__ __launch_bounds__(256) void k_resample(
    const int* __restrict__ flag, const float* __restrict__ att,
    const float* __restrict__ Mv, const float* __restrict__ Sv,
    const int* __restrict__ mask, float* __restrict__ out) {
  const int b = blockIdx.x * 256 + threadIdx.x;
  if (b >= NB) return;
  if (!flag[b]) return;
  float best = -INFINITY;
  int bj = 0;
  for (int j = 0; j < 28; ++j) {
    float y = (att[b * 28 + j] - Mv[j]) - logf(Sv[j]) + gumbel_for(b, j);
    if (y > best) { best = y; bj = j; }
  }
  out[b] = (float)bj;
  out[NB + b] = expf(att[b * 28 + bj] - Mv[bj]) / Sv[bj];
  const int* mrow = mask + b * NL;
#pragma unroll
  for (int l = 0; l < NL; ++l)
    out[2 * NB + (size_t)b * NL + l] = (float)(mrow[l] - ((l == bj) ? 1 : 0));
}

extern "C" void kernel_launch(void* const* d_in, const int* in_sizes, int n_in,
                              void* d_out, int out_size, void* d_ws, size_t ws_size,
                              hipStream_t stream) {
  const float* enc  = (const float*)d_in[0];
  const int*   xes  = (const int*)d_in[1];
  const int*   idx  = (const int*)d_in[2];
  const int*   mask = (const int*)d_in[3];
  const float* Wq   = (const float*)d_in[4];
  const float* bq   = (const float*)d_in[5];
  const float* Wc   = (const float*)d_in[6];
  const float* bc   = (const float*)d_in[7];
  const float* V4   = (const float*)d_in[8];
  const float* Wi   = (const float*)d_in[9];
  const float* bi   = (const float*)d_in[10];
  const float* Wh   = (const float*)d_in[11];
  const float* Wv   = (const float*)d_in[12];
  const float* Wsh  = (const float*)d_in[13];
  const float* Wsv  = (const float*)d_in[14];
  const float* We   = (const float*)d_in[15];
  (void)in_sizes; (void)n_in; (void)out_size; (void)ws_size;

  float* edge_all = (float*)d_ws;                          // [5*NB, NH]
  float* st       = edge_all + (size_t)NSTEP * NB * NH;    // [NB, NH]
  float* lin      = st + (size_t)NB * NH;                  // [NB, NH]
  float* query    = lin + (size_t)NB * NH;                 // [NB, NH]
  float* inp      = query + (size_t)NB * NH;               // [NB, NH]
  float* att      = inp + (size_t)NB * NH;                 // [NB, 28]
  float* Mv       = att + (size_t)NB * 28;                 // [28]
  float* Sv       = Mv + 28;                               // [28]
  int*   flag     = (int*)(Sv + 28);                       // [NB]
  int*   cnt      = flag + NB;                             // [1]
  int*   list     = cnt + 4;                               // [NB]
  unsigned short* enc_hi = (unsigned short*)(list + NB);   // [NB*NL, ND]
  unsigned short* enc_lo = enc_hi + (size_t)NB * NL * ND;
  unsigned short* wc_hi  = enc_lo + (size_t)NB * NL * ND;  // [4*NH, ND]
  unsigned short* wc_lo  = wc_hi + (size_t)4 * NH * ND;
  float* out      = (float*)d_out;

  hipMemsetAsync(st, 0, (size_t)NB * NH * sizeof(float), stream);
  hipMemsetAsync(att, 0, (size_t)NB * 28 * sizeof(float), stream);
  hipMemsetAsync(cnt, 0, sizeof(int), stream);

  dim3 blk(256);
  k_split<<<dim3((NB * NL * ND) / 1024), blk, 0, stream>>>(enc, enc_hi, enc_lo);
  k_split<<<dim3((4 * NH * ND) / 1024), blk, 0, stream>>>(Wc, wc_hi, wc_lo);
  g1_edge<<<dim3(16, 320), blk, 0, stream>>>(enc, xes, Wh, Wv, Wsh, Wsv, edge_all);
  gemm_bias<<<dim3(16, 64), blk, 0, stream>>>(nullptr, idx, enc, Wi, bi, lin);
  g2_stmax<<<dim3(16, 320), blk, 0, stream>>>(edge_all, We, (unsigned*)st);
  k_query<<<dim3((NB * NH) / 256), blk, 0, stream>>>(edge_all, st, lin, query);
  gemm_bias<<<dim3(16, 64), blk, 0, stream>>>(query, nullptr, enc, Wq, bq, inp);
  g5_mfma<<<dim3(224, 32), blk, 0, stream>>>(enc_hi, enc_lo, wc_hi, wc_lo,
                                             inp, bc, V4, att);
  k_finish<<<dim3((NB * 28) / 256), blk, 0, stream>>>(att, mask);
  k_colstats<<<dim3(28), blk, 0, stream>>>(att, Mv, Sv);
  k_sample<<<dim3(NB / 256), blk, 0, stream>>>(att, Mv, Sv, mask, out, flag, cnt, list);
  k_fixup_att<<<dim3(4, 64), blk, 0, stream>>>(cnt, list, enc, Wc, bc, V4, inp, mask, att);
  k_resample<<<dim3(NB / 256), blk, 0, stream>>>(flag, att, Mv, Sv, mask, out);
}